// Round 5
// baseline (33.953 us; speedup 1.0000x reference)
//
#include <hip/hip_runtime.h>

#define HW 56
#define PLANE 3136     // 56*56
#define CH 64          // channels after pair-sum
#define CI 32          // output channels
#define NI 4           // output channels per thread
#define WPAIRS 28      // float2 groups per row
#define P2 (HW*WPAIRS) // 1568 float2 pixel-groups

// Single kernel: inline pair-sum + 3-tap H conv + fused roll.
// grid = (25, 8), block = 64 (one wave). 25*64 = 1600 >= 1568 pixel-pairs.
// Each thread: 2 adjacent w outputs x 4 adjacent i channels.
__global__ __launch_bounds__(64) void convshift_kernel(
    const float* __restrict__ x, const float* __restrict__ Wt, float* __restrict__ out)
{
    const int i0 = blockIdx.y * NI;
    const int pp = blockIdx.x * 64 + threadIdx.x;
    const int pc = (pp < P2) ? pp : (P2 - 1);     // clamp tail threads to safe addrs
    const int h  = pc / WPAIRS;
    const int wp = pc - h * WPAIRS;
    const int w0 = wp * 2;

    const bool v0 = (h > 0), v2 = (h < HW - 1);
    const int hm = v0 ? h - 1 : 0;                // clamped rows; contribution masked at end
    const int hp = v2 ? h + 1 : HW - 1;

    const float* __restrict__ a0p = x + hm * HW + w0;                // first-half channels
    const float* __restrict__ a1p = x + h  * HW + w0;
    const float* __restrict__ a2p = x + hp * HW + w0;
    const float* __restrict__ b0p = a0p + CH * PLANE;                // second-half channels
    const float* __restrict__ b1p = a1p + CH * PLANE;
    const float* __restrict__ b2p = a2p + CH * PLANE;

    const float* __restrict__ Wp = Wt + i0 * (CH * 3);  // wave-uniform -> s_load

    // per-tap, per-i accumulators (masked combine at end)
    float2 ac0[NI], ac1[NI], ac2[NI];
    #pragma unroll
    for (int ii = 0; ii < NI; ++ii) {
        ac0[ii] = make_float2(0.f, 0.f);
        ac1[ii] = make_float2(0.f, 0.f);
        ac2[ii] = make_float2(0.f, 0.f);
    }

    // double-buffered register staging: 4 channels x 3 rows x 2 halves in flight
    float2 A0[2][4], A1[2][4], A2[2][4], B0[2][4], B1[2][4], B2[2][4];

    #pragma unroll
    for (int j = 0; j < 4; ++j) {
        const int o = j * PLANE;
        A0[0][j] = *(const float2*)(a0p + o);
        A1[0][j] = *(const float2*)(a1p + o);
        A2[0][j] = *(const float2*)(a2p + o);
        B0[0][j] = *(const float2*)(b0p + o);
        B1[0][j] = *(const float2*)(b1p + o);
        B2[0][j] = *(const float2*)(b2p + o);
    }

    #pragma unroll
    for (int ch = 0; ch < 16; ++ch) {
        const int cur = ch & 1, nxt = cur ^ 1;
        if (ch < 15) {
            #pragma unroll
            for (int j = 0; j < 4; ++j) {
                const int o = ((ch + 1) * 4 + j) * PLANE;
                A0[nxt][j] = *(const float2*)(a0p + o);
                A1[nxt][j] = *(const float2*)(a1p + o);
                A2[nxt][j] = *(const float2*)(a2p + o);
                B0[nxt][j] = *(const float2*)(b0p + o);
                B1[nxt][j] = *(const float2*)(b1p + o);
                B2[nxt][j] = *(const float2*)(b2p + o);
            }
        }
        #pragma unroll
        for (int j = 0; j < 4; ++j) {
            const int c = ch * 4 + j;
            // inline pair-sum
            float2 s0, s1, s2;
            s0.x = A0[cur][j].x + B0[cur][j].x;  s0.y = A0[cur][j].y + B0[cur][j].y;
            s1.x = A1[cur][j].x + B1[cur][j].x;  s1.y = A1[cur][j].y + B1[cur][j].y;
            s2.x = A2[cur][j].x + B2[cur][j].x;  s2.y = A2[cur][j].y + B2[cur][j].y;
            #pragma unroll
            for (int ii = 0; ii < NI; ++ii) {
                const float wk0 = Wp[ii * (CH * 3) + c * 3 + 0];  // uniform -> SGPR
                const float wk1 = Wp[ii * (CH * 3) + c * 3 + 1];
                const float wk2 = Wp[ii * (CH * 3) + c * 3 + 2];
                ac0[ii].x += s0.x * wk0;  ac0[ii].y += s0.y * wk0;
                ac1[ii].x += s1.x * wk1;  ac1[ii].y += s1.y * wk1;
                ac2[ii].x += s2.x * wk2;  ac2[ii].y += s2.y * wk2;
            }
        }
    }

    if (pp < P2) {
        #pragma unroll
        for (int ii = 0; ii < NI; ++ii) {
            float rx = ac1[ii].x, ry = ac1[ii].y;
            if (v0) { rx += ac0[ii].x; ry += ac0[ii].y; }
            if (v2) { rx += ac2[ii].x; ry += ac2[ii].y; }
            // fuse jnp.roll(+1, axis=w): value at w stored at w+1
            float* orow = out + (i0 + ii) * PLANE + h * HW;
            orow[w0 + 1] = rx;                       // w0+1 <= 55, never wraps
            int ws2 = w0 + 2; if (ws2 == HW) ws2 = 0;
            orow[ws2] = ry;
        }
    }
}

extern "C" void kernel_launch(void* const* d_in, const int* in_sizes, int n_in,
                              void* d_out, int out_size, void* d_ws, size_t ws_size,
                              hipStream_t stream) {
    const float* x  = (const float*)d_in[0];   // (1,128,56,56) f32
    const float* Wt = (const float*)d_in[1];   // (32,64,3) f32
    float* out = (float*)d_out;                // (1,32,56,56) f32

    dim3 grid(25, CI / NI), block(64);
    hipLaunchKernelGGL(convshift_kernel, grid, block, 0, stream, x, Wt, out);
}

// Round 9
// 12.015 us; speedup vs baseline: 2.8259x; 2.8259x over previous
//
#include <hip/hip_runtime.h>

#define HW 56
#define PLANE 3136     // 56*56
#define CH 64          // channels after pair-sum
#define CI 32          // output channels
#define NI 2           // output channels per thread

// Single kernel: inline pair-sum + 3-tap H conv + fused roll.
// grid = (13, 16), block = 256. 13*256 = 3328 >= 3136 pixels; each thread
// computes 1 pixel x 2 adjacent output channels. 208 blocks = 832 waves.
__global__ __launch_bounds__(256) void convshift_kernel(
    const float* __restrict__ x, const float* __restrict__ Wt, float* __restrict__ out)
{
    __shared__ float sW[NI * CH * 3];            // 384 floats
    const int i0  = blockIdx.y * NI;
    const int tid = threadIdx.x;
    #pragma unroll
    for (int t = tid; t < NI * CH * 3; t += 256)
        sW[t] = Wt[i0 * (CH * 3) + t];
    __syncthreads();

    const int p  = blockIdx.x * 256 + tid;
    const int pc = (p < PLANE) ? p : (PLANE - 1);   // clamp tail threads to safe addrs
    const int h  = pc / HW;
    const int w  = pc - h * HW;

    const bool v0 = (h > 0), v2 = (h < HW - 1);
    const int hm = v0 ? h - 1 : 0;                  // clamped rows; masked at end
    const int hp = v2 ? h + 1 : HW - 1;

    const float* __restrict__ xa = x + w;                 // first 64 channels
    const float* __restrict__ xb = x + CH * PLANE + w;    // second 64 channels
    const int r0 = hm * HW, r1 = h * HW, r2 = hp * HW;

    // accumulators: [i][tap], merged+masked at end
    float acc[NI][3];
    #pragma unroll
    for (int ii = 0; ii < NI; ++ii) { acc[ii][0] = 0.f; acc[ii][1] = 0.f; acc[ii][2] = 0.f; }

    // double-buffered register staging: 8 channels x 3 rows x 2 halves in flight
    float A0[2][8], A1[2][8], A2[2][8], B0[2][8], B1[2][8], B2[2][8];

    #pragma unroll
    for (int j = 0; j < 8; ++j) {
        const int o = j * PLANE;
        A0[0][j] = xa[o + r0]; A1[0][j] = xa[o + r1]; A2[0][j] = xa[o + r2];
        B0[0][j] = xb[o + r0]; B1[0][j] = xb[o + r1]; B2[0][j] = xb[o + r2];
    }

    #pragma unroll
    for (int ch = 0; ch < 8; ++ch) {
        const int cur = ch & 1, nxt = cur ^ 1;
        if (ch < 7) {
            #pragma unroll
            for (int j = 0; j < 8; ++j) {
                const int o = ((ch + 1) * 8 + j) * PLANE;
                A0[nxt][j] = xa[o + r0]; A1[nxt][j] = xa[o + r1]; A2[nxt][j] = xa[o + r2];
                B0[nxt][j] = xb[o + r0]; B1[nxt][j] = xb[o + r1]; B2[nxt][j] = xb[o + r2];
            }
        }
        #pragma unroll
        for (int j = 0; j < 8; ++j) {
            const int c = ch * 8 + j;
            // pair-sum once, reuse across NI output channels
            const float s0 = A0[cur][j] + B0[cur][j];
            const float s1 = A1[cur][j] + B1[cur][j];
            const float s2 = A2[cur][j] + B2[cur][j];
            #pragma unroll
            for (int ii = 0; ii < NI; ++ii) {
                acc[ii][0] += s0 * sW[ii * (CH * 3) + c * 3 + 0];
                acc[ii][1] += s1 * sW[ii * (CH * 3) + c * 3 + 1];
                acc[ii][2] += s2 * sW[ii * (CH * 3) + c * 3 + 2];
            }
        }
    }

    if (p < PLANE) {
        // fuse jnp.roll(+1, axis=w): value at w stored at (w+1) % 56
        int wst = w + 1; if (wst == HW) wst = 0;
        #pragma unroll
        for (int ii = 0; ii < NI; ++ii) {
            float r = acc[ii][1];
            if (v0) r += acc[ii][0];
            if (v2) r += acc[ii][2];
            out[(i0 + ii) * PLANE + h * HW + wst] = r;
        }
    }
}

extern "C" void kernel_launch(void* const* d_in, const int* in_sizes, int n_in,
                              void* d_out, int out_size, void* d_ws, size_t ws_size,
                              hipStream_t stream) {
    const float* x  = (const float*)d_in[0];   // (1,128,56,56) f32
    const float* Wt = (const float*)d_in[1];   // (32,64,3) f32
    float* out = (float*)d_out;                // (1,32,56,56) f32

    dim3 grid(13, CI / NI), block(256);
    hipLaunchKernelGGL(convshift_kernel, grid, block, 0, stream, x, Wt, out);
}